// Round 1
// baseline (60.353 us; speedup 1.0000x reference)
//
#include <hip/hip_runtime.h>
#include <math.h>

// Problem constants (B=8, H=W=64, P=60 frequencies, N=4096 grid points)
#define NBATCH 8
#define NP 60
#define NG 64
#define NN 4096

// One block per (b, p) pair. 256 threads = 4 waves of 64.
__global__ __launch_bounds__(256) void chf_stage_kernel(
    const float* __restrict__ dnn, const float* __restrict__ gt,
    float* __restrict__ ws)
{
    // Twiddle table: cT[j*64 + k] = cos(0.4*(k-30)*(2j+1)), k<60 (freq), j<64 (grid).
    // angle = r_k * u_j with r_k=(k-30)*0.1, u_j = 8j+4 -> 0.4*(k-30)*(2j+1), exact int inside.
    __shared__ float cT[4096];
    __shared__ float sT[4096];
    __shared__ float Pre[256];
    __shared__ float Pim[256];
    __shared__ float Gre[64];
    __shared__ float Gim[64];

    const int t    = threadIdx.x;
    const int blk  = blockIdx.x;
    const int b    = blk / NP;
    const int p    = blk % NP;
    const int lane = t & 63;
    const int g    = t >> 6;   // wave id 0..3

    // ---- Phase 0: build twiddle table (16 sincos per thread) ----
    for (int i = t; i < 4096; i += 256) {
        const int j = i >> 6;      // grid index
        const int k = i & 63;      // freq index
        float c = 0.f, s = 0.f;
        if (k < NP) {
            const float a = 0.4f * (float)((k - 30) * (2 * j + 1));
            sincosf(a, &s, &c);
        }
        cT[i] = c;
        sT[i] = s;
    }
    __syncthreads();

    // ---- Phase 1: G[w] = sum_h (c + i s)(r_p, y_h) * d[h][w] ----
    // lane = w (coalesced global reads), wave g covers h in [16g, 16g+16)
    {
        const float* ob = dnn + b * NN;
        const float* gb = gt  + b * NN;
        float gr = 0.f, gi = 0.f;
        const int h0 = g * 16;
        #pragma unroll
        for (int hh = 0; hh < 16; ++hh) {
            const int h = h0 + hh;
            const float d = ob[h * 64 + lane] - gb[h * 64 + lane];
            const float c = cT[h * 64 + p];   // wave-broadcast
            const float s = sT[h * 64 + p];
            gr = fmaf(c, d, gr);
            gi = fmaf(s, d, gi);
        }
        Pre[t] = gr;
        Pim[t] = gi;
    }
    __syncthreads();
    if (t < 64) {
        Gre[t] = Pre[t] + Pre[64 + t] + Pre[128 + t] + Pre[192 + t];
        Gim[t] = Pim[t] + Pim[64 + t] + Pim[128 + t] + Pim[192 + t];
    }
    __syncthreads();

    // ---- Phase 2: F[q] = sum_w (c + i s)(r_q, x_w) * G[w] ----
    // lane = q (bank stride 64 floats -> 2-way, free), wave g covers w chunk
    {
        float fr = 0.f, fi = 0.f;
        const int w0 = g * 16;
        #pragma unroll
        for (int ww = 0; ww < 16; ++ww) {
            const int w = w0 + ww;
            const float c  = cT[w * 64 + lane];
            const float s  = sT[w * 64 + lane];
            const float xr = Gre[w];          // wave-broadcast
            const float xi = Gim[w];
            fr += c * xr - s * xi;
            fi += c * xi + s * xr;
        }
        Pre[t] = fr;
        Pim[t] = fi;
    }
    __syncthreads();

    // ---- Reduce sum_q |F[q]|^2 over wave 0, write one partial per block ----
    if (t < 64) {
        const float Fr = Pre[t] + Pre[64 + t] + Pre[128 + t] + Pre[192 + t];
        const float Fi = Pim[t] + Pim[64 + t] + Pim[128 + t] + Pim[192 + t];
        float val = (t < NP) ? (Fr * Fr + Fi * Fi) : 0.f;
        #pragma unroll
        for (int off = 32; off > 0; off >>= 1)
            val += __shfl_down(val, off);
        if (t == 0) ws[blk] = val;  // ws[b*60 + p] = partial sum of squares
    }
}

// Single block: wave b reduces its 60 partials, sqrt, thread 0 sums & scales.
__global__ __launch_bounds__(512) void chf_final_kernel(
    const float* __restrict__ ws, float* __restrict__ outp)
{
    __shared__ float sq[NBATCH];
    const int t    = threadIdx.x;
    const int b    = t >> 6;
    const int lane = t & 63;
    float v = (lane < NP) ? ws[b * NP + lane] : 0.f;
    #pragma unroll
    for (int off = 32; off > 0; off >>= 1)
        v += __shfl_down(v, off);
    if (lane == 0) sq[b] = sqrtf(v);
    __syncthreads();
    if (t == 0) {
        float sum = 0.f;
        #pragma unroll
        for (int i = 0; i < NBATCH; ++i) sum += sq[i];
        outp[0] = sum * (0.1f / (float)NBATCH);  // CHF_TIK * mean over batch
    }
}

extern "C" void kernel_launch(void* const* d_in, const int* in_sizes, int n_in,
                              void* d_out, int out_size, void* d_ws, size_t ws_size,
                              hipStream_t stream)
{
    const float* dnn = (const float*)d_in[0];
    const float* gt  = (const float*)d_in[1];
    float* outp = (float*)d_out;
    float* ws   = (float*)d_ws;   // needs 480 floats

    chf_stage_kernel<<<NBATCH * NP, 256, 0, stream>>>(dnn, gt, ws);
    chf_final_kernel<<<1, 512, 0, stream>>>(ws, outp);
}

// Round 2
// 57.426 us; speedup vs baseline: 1.0510x; 1.0510x over previous
//
#include <hip/hip_runtime.h>
#include <math.h>

// Problem constants (B=8, H=W=64, P=60 frequencies, N=4096 grid points)
#define NBATCH 8
#define NP 60
#define NG 64
#define NN 4096

// One block per (b, p) pair. 256 threads = 4 waves of 64.
// Twiddles cos/sin(0.4*(k-30)*(2j+1)) are generated by per-thread complex
// recurrence (2 sincosf + 15 rotations per phase) -- no LDS table, no phase-0.
__global__ __launch_bounds__(256) void chf_stage_kernel(
    const float* __restrict__ dnn, const float* __restrict__ gt,
    float* __restrict__ ws)
{
    __shared__ float Pre[256];
    __shared__ float Pim[256];
    __shared__ float Gre[64];
    __shared__ float Gim[64];

    const int t    = threadIdx.x;
    const int blk  = blockIdx.x;
    const int b    = blk / NP;
    const int p    = blk % NP;
    const int lane = t & 63;
    const int g    = t >> 6;   // wave id 0..3

    // ---- Phase 1: G[w] = sum_h e^{i r_p y_h} * d[h][w] ----
    // lane = w (coalesced), wave g covers h in [16g, 16g+16).
    // angle(h) = 0.4*(p-30)*(2h+1); step per h: 0.8*(p-30).
    {
        const float fp = 0.4f * (float)(p - 30);
        float c, s, cs, ss;
        sincosf(fp * (float)(32 * g + 1), &s, &c);   // base at h = 16g
        sincosf(fp * 2.0f, &ss, &cs);                // per-row step
        float gr = 0.f, gi = 0.f;
        const float* ob = dnn + b * NN + g * 16 * 64 + lane;
        const float* gb = gt  + b * NN + g * 16 * 64 + lane;
        #pragma unroll
        for (int hh = 0; hh < 16; ++hh) {
            const float d = ob[hh * 64] - gb[hh * 64];
            gr = fmaf(c, d, gr);
            gi = fmaf(s, d, gi);
            const float cn = fmaf(c, cs, -(s * ss));
            const float sn = fmaf(s, cs,  (c * ss));
            c = cn; s = sn;
        }
        Pre[t] = gr;
        Pim[t] = gi;
    }
    __syncthreads();
    if (t < 64) {
        Gre[t] = Pre[t] + Pre[64 + t] + Pre[128 + t] + Pre[192 + t];
        Gim[t] = Pim[t] + Pim[64 + t] + Pim[128 + t] + Pim[192 + t];
    }
    __syncthreads();

    // ---- Phase 2: F[q] = sum_w e^{i r_q x_w} * G[w] ----
    // lane = q (its own fixed frequency), wave g covers w in [16g, 16g+16).
    // angle(w) = 0.4*(lane-30)*(2w+1); step per w: 0.8*(lane-30).
    {
        const float fq = 0.4f * (float)(lane - 30);
        float c, s, cs, ss;
        sincosf(fq * (float)(32 * g + 1), &s, &c);   // base at w = 16g
        sincosf(fq * 2.0f, &ss, &cs);
        float fr = 0.f, fi = 0.f;
        #pragma unroll
        for (int ww = 0; ww < 16; ++ww) {
            const int w = g * 16 + ww;
            const float xr = Gre[w];   // wave-broadcast
            const float xi = Gim[w];
            fr += c * xr - s * xi;
            fi += c * xi + s * xr;
            const float cn = fmaf(c, cs, -(s * ss));
            const float sn = fmaf(s, cs,  (c * ss));
            c = cn; s = sn;
        }
        Pre[t] = fr;
        Pim[t] = fi;
    }
    __syncthreads();

    // ---- Reduce sum_q |F[q]|^2 over wave 0, one partial per block ----
    // Lanes 60..63 computed finite garbage (unused frequencies) -> gated out.
    if (t < 64) {
        const float Fr = Pre[t] + Pre[64 + t] + Pre[128 + t] + Pre[192 + t];
        const float Fi = Pim[t] + Pim[64 + t] + Pim[128 + t] + Pim[192 + t];
        float val = (t < NP) ? (Fr * Fr + Fi * Fi) : 0.f;
        #pragma unroll
        for (int off = 32; off > 0; off >>= 1)
            val += __shfl_down(val, off);
        if (t == 0) ws[blk] = val;  // ws[b*60 + p]
    }
}

// Single block: wave b reduces its 60 partials, sqrt, thread 0 sums & scales.
__global__ __launch_bounds__(512) void chf_final_kernel(
    const float* __restrict__ ws, float* __restrict__ outp)
{
    __shared__ float sq[NBATCH];
    const int t    = threadIdx.x;
    const int b    = t >> 6;
    const int lane = t & 63;
    float v = (lane < NP) ? ws[b * NP + lane] : 0.f;
    #pragma unroll
    for (int off = 32; off > 0; off >>= 1)
        v += __shfl_down(v, off);
    if (lane == 0) sq[b] = sqrtf(v);
    __syncthreads();
    if (t == 0) {
        float sum = 0.f;
        #pragma unroll
        for (int i = 0; i < NBATCH; ++i) sum += sq[i];
        outp[0] = sum * (0.1f / (float)NBATCH);  // CHF_TIK * mean over batch
    }
}

extern "C" void kernel_launch(void* const* d_in, const int* in_sizes, int n_in,
                              void* d_out, int out_size, void* d_ws, size_t ws_size,
                              hipStream_t stream)
{
    const float* dnn = (const float*)d_in[0];
    const float* gt  = (const float*)d_in[1];
    float* outp = (float*)d_out;
    float* ws   = (float*)d_ws;   // needs 480 floats

    chf_stage_kernel<<<NBATCH * NP, 256, 0, stream>>>(dnn, gt, ws);
    chf_final_kernel<<<1, 512, 0, stream>>>(ws, outp);
}